// Round 7
// baseline (165.801 us; speedup 1.0000x reference)
//
#include <hip/hip_runtime.h>
#include <stdint.h>

// FP4 quant-dequant, faithful to the JAX reference in float32 arithmetic.
// v7: no-LDS k_scales. Data stays in the coalesced layout (lane = 4 consecutive
// elements; block = 16 consecutive lanes). Per-block top-5 via sorted-list
// butterfly merges (shuffle xor 1,2,4,8). Each lane quantizes its own 4
// registers and stores one packed u32 -> all global traffic lane-contiguous.

#define BLK 64
#define WG 256
#define ITERS 8                      // 256-elem chunks per wave
#define FLT_BIG 3.402823466e+38f

// Merge two descending sorted 5-lists into the descending top-5 of the union.
// C[k] = max(A[k], B[k], max_{i+j=k-1} min(A[i],B[j])) — exact selection by
// value (multiset semantics), no ties/index issues.
__device__ __forceinline__ void merge5(float (&A)[5], const float (&B)[5]) {
    const float ab00 = fminf(A[0], B[0]);
    const float ab10 = fminf(A[1], B[0]), ab01 = fminf(A[0], B[1]);
    const float ab20 = fminf(A[2], B[0]), ab11 = fminf(A[1], B[1]), ab02 = fminf(A[0], B[2]);
    const float ab30 = fminf(A[3], B[0]), ab21 = fminf(A[2], B[1]),
                ab12 = fminf(A[1], B[2]), ab03 = fminf(A[0], B[3]);
    float C0 = fmaxf(A[0], B[0]);
    float C1 = fmaxf(fmaxf(A[1], B[1]), ab00);
    float C2 = fmaxf(fmaxf(A[2], B[2]), fmaxf(ab10, ab01));
    float C3 = fmaxf(fmaxf(A[3], B[3]), fmaxf(ab20, fmaxf(ab11, ab02)));
    float C4 = fmaxf(fmaxf(A[4], B[4]),
                     fmaxf(fmaxf(ab30, ab21), fmaxf(ab12, ab03)));
    A[0] = C0; A[1] = C1; A[2] = C2; A[3] = C3; A[4] = C4;
}

// 4 * nearest FP4 level via boundary ladder (integers, exact).
// Equivalent to first-index argmin over the FP4 table: midpoints are exact
// dyadics; midpoint ties go to the lower-index level in both formulations.
__device__ __forceinline__ int qlvl4(float xn) {
    int bv = -12;
    bv += (xn > -2.5f)   ? 4 : 0;
    bv += (xn > -1.75f)  ? 2 : 0;
    bv += (xn > -1.25f)  ? 2 : 0;
    bv += (xn > -0.875f) ? 1 : 0;
    bv += (xn > -0.375f) ? 3 : 0;
    bv += (xn > 0.375f)  ? 3 : 0;
    bv += (xn > 0.875f)  ? 1 : 0;
    bv += (xn > 1.25f)   ? 2 : 0;
    bv += (xn > 1.75f)   ? 2 : 0;
    bv += (xn > 2.5f)    ? 4 : 0;
    return bv;
}

// Double-quantized scale, pre-divided by 4 (pairs with 4*level; /4 and *4 are
// exact power-of-two scalings => bit-identical to lvl*ds).
__device__ __forceinline__ float dscale4(float s, float smin, float smax) {
    if (smax > smin) {
        const float ss = __fdiv_rn(__fsub_rn(smax, smin), 255.0f);
        float q = rintf(__fdiv_rn(__fsub_rn(s, smin), ss));   // round half-even
        q = fminf(fmaxf(q, 0.0f), 255.0f);                    // clip AFTER round
        return __fmul_rn(q, ss) * 0.25f;
    }
    return 0.0f;   // q=0, scale_scale=1 -> deq 0
}

template <bool STORE_LEVELS>
__global__ __launch_bounds__(WG) void k_scales(const float* __restrict__ x,
                                               long n, int nblocks,
                                               float* __restrict__ scales,
                                               uint32_t* __restrict__ levels,
                                               uint32_t* __restrict__ hdr) {
    const int lane = threadIdx.x & 63;
    const int wvi = threadIdx.x >> 6;
    const long waveBase = ((long)(blockIdx.x * 4 + wvi)) * (ITERS * 256);

    float lmin = FLT_BIG, lmax = 0.0f;

    for (int it = 0; it < ITERS; ++it) {
        const long ebase = waveBase + (long)it * 256;   // wave-uniform
        if (ebase >= n) break;
        const long ei = ebase + (long)lane * 4;          // this lane's 4 elems

        float4 xv;
        if (ebase + 256 <= n) {
            xv = *reinterpret_cast<const float4*>(x + ei);
        } else {
            float tmp[4];
            for (int d = 0; d < 4; ++d)
                tmp[d] = (ei + d < n) ? x[ei + d] : 0.0f;  // reference zero-pads
            xv = make_float4(tmp[0], tmp[1], tmp[2], tmp[3]);
        }

        // Sort |x| descending (5-CE network); pad 5th with 0 (abs >= 0).
        float a = fabsf(xv.x), b = fabsf(xv.y), c = fabsf(xv.z), d = fabsf(xv.w);
        float t;
        t = fmaxf(a, b); b = fminf(a, b); a = t;
        t = fmaxf(c, d); d = fminf(c, d); c = t;
        t = fmaxf(a, c); c = fminf(a, c); a = t;
        t = fmaxf(b, d); d = fminf(b, d); b = t;
        t = fmaxf(b, c); c = fminf(b, c); b = t;
        float A[5] = {a, b, c, d, 0.0f};

        // Butterfly merge across the block's 16 lanes.
#pragma unroll
        for (int dlt = 1; dlt < 16; dlt <<= 1) {
            float B[5];
#pragma unroll
            for (int k = 0; k < 5; ++k) B[k] = __shfl_xor(A[k], dlt, 64);
            merge5(A, B);
        }

        // JAX f32 quantile: q = 0.95f*63.0f; result = v59*lw + v60*hw
        const float qs = 0.95f * 63.0f;     // 59.849998474121094f
        const float hw = qs - 59.0f;
        const float lw = 60.0f - qs;
        float s = __fadd_rn(__fmul_rn(A[4], lw), __fmul_rn(A[3], hw));
        s = fmaxf(s, 1e-8f);

        const int blk = (int)(ei >> 6);
        const bool bval = (blk < nblocks);
        if (bval) {
            lmin = fminf(lmin, s);
            lmax = fmaxf(lmax, s);
            if ((lane & 15) == 0) scales[blk] = s;
        }

        if (STORE_LEVELS && ei < n) {
            const int a0 = qlvl4(__fdiv_rn(xv.x, s));
            const int a1 = qlvl4(__fdiv_rn(xv.y, s));
            const int a2 = qlvl4(__fdiv_rn(xv.z, s));
            const int a3 = qlvl4(__fdiv_rn(xv.w, s));
            const uint32_t pw = (uint32_t)(a0 & 255) | ((uint32_t)(a1 & 255) << 8) |
                                ((uint32_t)(a2 & 255) << 16) | ((uint32_t)(a3 & 255) << 24);
            levels[ei >> 2] = pw;           // lane-contiguous, coalesced
        }
    }

    // Wave min/max reduce -> tiny LDS cross-wave -> one atomic pair per WG.
#pragma unroll
    for (int off = 32; off > 0; off >>= 1) {
        lmin = fminf(lmin, __shfl_xor(lmin, off, 64));
        lmax = fmaxf(lmax, __shfl_xor(lmax, off, 64));
    }
    __shared__ float smn[4], smx[4];
    if (lane == 0) { smn[wvi] = lmin; smx[wvi] = lmax; }
    __syncthreads();
    if (threadIdx.x == 0) {
        float fmn = smn[0], fmx = smx[0];
#pragma unroll
        for (int i = 1; i < 4; ++i) { fmn = fminf(fmn, smn[i]); fmx = fmaxf(fmx, smx[i]); }
        // uint order == float order for positive floats; s >= 1e-8 > 0.
        atomicMin(&hdr[0], __float_as_uint(fmn));
        atomicMax(&hdr[1], __float_as_uint(fmx));
    }
}

__global__ __launch_bounds__(WG) void k_deq(const uint32_t* __restrict__ levels,
                                            const float* __restrict__ scales,
                                            const uint32_t* __restrict__ hdr,
                                            long n, int nwords,
                                            float* __restrict__ out) {
    const int t = blockIdx.x * WG + threadIdx.x;
    if (t >= nwords) return;
    const float smin = __uint_as_float(hdr[0]);
    const float smax = __uint_as_float(hdr[1]);
    const float s = scales[t >> 4];
    const float ds4 = dscale4(s, smin, smax);

    const uint32_t wv = levels[t];
    const long i = (long)t * 4;
    if (i + 3 < n) {
        float4 ov;
        ov.x = __fmul_rn((float)(int)(int8_t)(wv), ds4);
        ov.y = __fmul_rn((float)(int)(int8_t)(wv >> 8), ds4);
        ov.z = __fmul_rn((float)(int)(int8_t)(wv >> 16), ds4);
        ov.w = __fmul_rn((float)(int)(int8_t)(wv >> 24), ds4);
        *reinterpret_cast<float4*>(out + i) = ov;
    } else {
        for (int k = 0; k < 4 && i + k < n; ++k)
            out[i + k] = __fmul_rn((float)(int)(int8_t)(wv >> (8 * k)), ds4);
    }
}

// Fallback if ws can't hold the levels array: re-quantize from x.
__global__ __launch_bounds__(WG) void k_quant(const float* __restrict__ x,
                                              const float* __restrict__ scales,
                                              const uint32_t* __restrict__ hdr,
                                              long n,
                                              float* __restrict__ out) {
    const long i = ((long)blockIdx.x * WG + threadIdx.x) * 4;
    if (i >= n) return;
    const float smin = __uint_as_float(hdr[0]);
    const float smax = __uint_as_float(hdr[1]);
    const float s = scales[i >> 6];
    const float ds4 = dscale4(s, smin, smax);

    if (i + 3 < n) {
        const float4 xv = *reinterpret_cast<const float4*>(x + i);
        float4 ov;
        ov.x = __fmul_rn((float)qlvl4(__fdiv_rn(xv.x, s)), ds4);
        ov.y = __fmul_rn((float)qlvl4(__fdiv_rn(xv.y, s)), ds4);
        ov.z = __fmul_rn((float)qlvl4(__fdiv_rn(xv.z, s)), ds4);
        ov.w = __fmul_rn((float)qlvl4(__fdiv_rn(xv.w, s)), ds4);
        *reinterpret_cast<float4*>(out + i) = ov;
    } else {
        for (int j = 0; j < 4 && i + j < n; ++j)
            out[i + j] = __fmul_rn((float)qlvl4(__fdiv_rn(x[i + j], s)), ds4);
    }
}

extern "C" void kernel_launch(void* const* d_in, const int* in_sizes, int n_in,
                              void* d_out, int out_size, void* d_ws, size_t ws_size,
                              hipStream_t stream) {
    const float* x = (const float*)d_in[0];
    float* out = (float*)d_out;
    const long n = in_sizes[0];
    const int nblocks = (int)((n + BLK - 1) / BLK);
    const int nwords = nblocks * 16;                       // packed u32 words
    const long perWG = (long)4 * ITERS * 256;              // 8192 elems per WG
    const int nwgScales = (int)((n + perWG - 1) / perWG);

    // ws layout: [hdr: 2 u32, padded to 16B] [scales: nblocks f32] [levels]
    uint32_t* hdr = (uint32_t*)d_ws;
    float* scales = (float*)((char*)d_ws + 16);
    uint32_t* levels = (uint32_t*)(scales + nblocks);
    const size_t need = 16 + (size_t)nblocks * 4 + (size_t)nwords * 4;
    const bool useLevels = (ws_size >= need);

    // hdr[0]=min init 0xFFFFFFFF (uint-max), hdr[1]=max init 0.
    hipMemsetAsync((void*)hdr, 0xFF, 4, stream);
    hipMemsetAsync((void*)((char*)d_ws + 4), 0x00, 4, stream);

    if (useLevels) {
        k_scales<true><<<nwgScales, WG, 0, stream>>>(x, n, nblocks, scales, levels, hdr);
        k_deq<<<(nwords + WG - 1) / WG, WG, 0, stream>>>(levels, scales, hdr, n, nwords, out);
    } else {
        k_scales<false><<<nwgScales, WG, 0, stream>>>(x, n, nblocks, scales, levels, hdr);
        k_quant<<<(int)((n / 4 + WG - 1) / WG), WG, 0, stream>>>(x, scales, hdr, n, out);
    }
}